// Round 2
// 2350.036 us; speedup vs baseline: 1.0318x; 1.0318x over previous
//
#include <hip/hip_runtime.h>
#include <hip/hip_bf16.h>
#include <math.h>

using bf16 = __hip_bfloat16;
typedef __bf16 bf16x8 __attribute__((ext_vector_type(8)));
typedef float f32x4 __attribute__((ext_vector_type(4)));

__device__ __forceinline__ float toF(float v) { return v; }
__device__ __forceinline__ float toF(bf16 v) { return __bfloat162float(v); }

__device__ __forceinline__ float gelu_f(float x) {
  float t = tanhf(0.7978845608028654f * (x + 0.044715f * x * x * x));
  return 0.5f * x * (1.0f + t);
}

__device__ __forceinline__ void gld_lds16(const bf16* g, bf16* l) {
  __builtin_amdgcn_global_load_lds(
      (const __attribute__((address_space(1))) void*)g,
      (__attribute__((address_space(3))) void*)l, 16, 0, 0);
}

__device__ __forceinline__ float block_sum(float v) {
  __shared__ float tmp[8];
  int lane = threadIdx.x & 63, w = threadIdx.x >> 6, nw = blockDim.x >> 6;
#pragma unroll
  for (int o = 32; o > 0; o >>= 1) v += __shfl_down(v, o, 64);
  __syncthreads();
  if (lane == 0) tmp[w] = v;
  __syncthreads();
  float r = 0.f;
  for (int i = 0; i < nw; ++i) r += tmp[i];
  return r;
}

__device__ __forceinline__ float block_max(float v) {
  __shared__ float tmp2[8];
  int lane = threadIdx.x & 63, w = threadIdx.x >> 6, nw = blockDim.x >> 6;
#pragma unroll
  for (int o = 32; o > 0; o >>= 1) v = fmaxf(v, __shfl_down(v, o, 64));
  __syncthreads();
  if (lane == 0) tmp2[w] = v;
  __syncthreads();
  float r = -1e30f;
  for (int i = 0; i < nw; ++i) r = fmaxf(r, tmp2[i]);
  return r;
}

// ---------------------------------------------------------------------------
// Generic MFMA GEMM: C = A * B^T-input (+ epilogue). A,B bf16; biases f32.
// A: [M,K] rows contiguous (stride lda). B: [N,K] rows contiguous (stride ldb).
// Batched z with decomposed strides (z = zh*zdiv + zw).
// EPI: 0 = bf16 out (+col bias if non-null)
//      2 = bf16 out, gelu(acc + col bias)
//      3 = resid[f32] += acc + col bias  (split-K capable: atomicAdd path)
//      4 = bf16 out, (acc + row bias) * mul[row*ldmul+col]
// trilskip: A lower-triangular in (m,k): skip k-tiles beyond m0+BM, zero k>m
//           on diagonal-straddling tiles.
// Split-K (kchunk > 0): grid.x = nxk * num_chunks; blockIdx.x decomposes into
//   (kc, n-tile). Each chunk covers K range [kc*kchunk, min(K,(kc+1)*kchunk)).
//   EPI==3 uses atomicAdd; col bias applied only by chunk 0.
// ---------------------------------------------------------------------------
template <int BM, int BN, int EPI>
__launch_bounds__((BM / 64) * (BN / 64) * 64)
__global__ void gemm_bt(const bf16* __restrict__ A, int lda, long sAzh, long sAzw,
                        const bf16* __restrict__ B, int ldb, long sBzh, long sBzw,
                        void* __restrict__ C, int ldc, long sCzh, long sCzw,
                        int M, int N, int K, int zdiv,
                        const float* __restrict__ bias,
                        const float* __restrict__ rowbias,
                        const bf16* __restrict__ mul, int ldmul,
                        float* __restrict__ resid, int trilskip,
                        int nxk, int kchunk) {
  constexpr int BK = 32;
  constexpr int WM = BM / 64, WN = BN / 64;
  constexpr int NT = WM * WN * 64;
  __shared__ __align__(16) bf16 As[BM * BK];
  __shared__ __align__(16) bf16 Bs[BN * BK];
  const int tid = threadIdx.x;
  const int wave = tid >> 6, lane = tid & 63;
  const int wm = wave / WN, wn = wave % WN;
  int bx = blockIdx.x, kc = 0;
  if (kchunk > 0) { kc = bx / nxk; bx -= kc * nxk; }
  const int m0 = blockIdx.y * BM, n0 = bx * BN;
  const int z = blockIdx.z;
  const int zh = z / zdiv, zw = z % zdiv;
  A += zh * sAzh + zw * sAzw;
  B += zh * sBzh + zw * sBzw;
  const long coff = zh * sCzh + zw * sCzw;

  f32x4 acc[4][4];
#pragma unroll
  for (int i = 0; i < 4; ++i)
#pragma unroll
    for (int j = 0; j < 4; ++j)
#pragma unroll
      for (int r = 0; r < 4; ++r) acc[i][j][r] = 0.0f;

  const int kbeg = (kchunk > 0) ? kc * kchunk : 0;
  int kend = K;
  if (kchunk > 0 && kbeg + kchunk < kend) kend = kbeg + kchunk;
  if (trilskip && m0 + BM < kend) kend = m0 + BM;
  const int lrow = lane & 15, lk = (lane >> 4) << 3;

  for (int k0 = kbeg; k0 < kend; k0 += BK) {
#pragma unroll
    for (int c = 0; c < (BM * BK) / (NT * 8); ++c) {
      int e = (c * NT + tid) << 3;
      int r = e >> 5, kk = e & 31;
      gld_lds16(A + (long)(m0 + r) * lda + (k0 + kk), As + e);
    }
#pragma unroll
    for (int c = 0; c < (BN * BK) / (NT * 8); ++c) {
      int e = (c * NT + tid) << 3;
      int r = e >> 5, kk = e & 31;
      gld_lds16(B + (long)(n0 + r) * ldb + (k0 + kk), Bs + e);
    }
    __syncthreads();
    if (trilskip && (k0 + BK > m0)) {  // diagonal-straddling tile: zero k>m
#pragma unroll
      for (int c = 0; c < (BM * BK) / (NT * 8); ++c) {
        int e = (c * NT + tid) << 3;
        int r = e >> 5, kk = e & 31;
        int m = m0 + r;
#pragma unroll
        for (int q = 0; q < 8; ++q)
          if (k0 + kk + q > m) As[e + q] = __float2bfloat16(0.0f);
      }
      __syncthreads();
    }
    bf16x8 af[4], bg[4];
#pragma unroll
    for (int i = 0; i < 4; ++i)
      af[i] = *(const bf16x8*)(As + (wm * 64 + i * 16 + lrow) * BK + lk);
#pragma unroll
    for (int j = 0; j < 4; ++j)
      bg[j] = *(const bf16x8*)(Bs + (wn * 64 + j * 16 + lrow) * BK + lk);
#pragma unroll
    for (int i = 0; i < 4; ++i)
#pragma unroll
      for (int j = 0; j < 4; ++j)
        acc[i][j] = __builtin_amdgcn_mfma_f32_16x16x32_bf16(af[i], bg[j], acc[i][j], 0, 0, 0);
    __syncthreads();
  }

  // epilogue: C/D mapping col = lane&15, row = (lane>>4)*4 + reg
  const int rbase = m0 + wm * 64 + ((lane >> 4) << 2);
  const int cbase = n0 + wn * 64 + (lane & 15);
#pragma unroll
  for (int i = 0; i < 4; ++i) {
#pragma unroll
    for (int j = 0; j < 4; ++j) {
#pragma unroll
      for (int r = 0; r < 4; ++r) {
        int row = rbase + i * 16 + r;
        int col = cbase + j * 16;
        float v = acc[i][j][r];
        long idx = coff + (long)row * ldc + col;
        if (EPI == 0) {
          if (bias) v += bias[col];
          ((bf16*)C)[idx] = __float2bfloat16(v);
        } else if (EPI == 2) {
          v += bias[col];
          ((bf16*)C)[idx] = __float2bfloat16(gelu_f(v));
        } else if (EPI == 3) {
          if (kchunk > 0) {
            if (kbeg == 0) v += bias[col];
            atomicAdd(&resid[idx], v);
          } else {
            v += bias[col];
            resid[idx] += v;
          }
        } else if (EPI == 4) {
          v += rowbias[row];
          v *= __bfloat162float(mul[(long)row * ldmul + col]);
          ((bf16*)C)[idx] = __float2bfloat16(v);
        }
      }
    }
  }
}

// ---------------------------------------------------------------------------
__global__ void k_embed(const int* __restrict__ tokens, const float* __restrict__ embed,
                        float* __restrict__ x) {
  int t = blockIdx.x;
  int tok = tokens[t];
  for (int j = threadIdx.x; j < 1024; j += 256)
    x[(long)t * 1024 + j] = embed[(long)tok * 1024 + j];
}

template <typename TIN>
__global__ void k_ln(const TIN* __restrict__ in, int ldin, const float* __restrict__ scale,
                     bf16* __restrict__ out, int ldout, int C) {
  int row = blockIdx.x, tid = threadIdx.x;
  const TIN* p = in + (long)row * ldin;
  float loc[8];
  int nper = C >> 8;
  float s = 0.f;
  for (int c = 0; c < nper; ++c) {
    float v = toF(p[c * 256 + tid]);
    loc[c] = v;
    s += v;
  }
  s = block_sum(s);
  float mean = s / (float)C;
  float s2 = 0.f;
  for (int c = 0; c < nper; ++c) {
    float d = loc[c] - mean;
    s2 += d * d;
  }
  s2 = block_sum(s2);
  float inv = 1.0f / sqrtf(s2 / (float)C + 1e-5f);
  for (int c = 0; c < nper; ++c) {
    int j = c * 256 + tid;
    out[(long)row * ldout + j] = __float2bfloat16((loc[c] - mean) * inv * scale[j]);
  }
}

// tiled transpose + cast to bf16: out[c][r] = bf16(in[r][c]); dims multiples of 32
template <typename TIN>
__global__ void k_transpose(const TIN* __restrict__ in, int ldin, bf16* __restrict__ out,
                            int ldout, int rows, int cols) {
  __shared__ bf16 tile[32][33];
  int c0 = blockIdx.x * 32, r0 = blockIdx.y * 32;
  int tx = threadIdx.x & 31, ty = threadIdx.x >> 5;  // 256 threads, ty 0..7
#pragma unroll
  for (int j = 0; j < 32; j += 8)
    tile[ty + j][tx] = __float2bfloat16(toF(in[(long)(r0 + ty + j) * ldin + c0 + tx]));
  __syncthreads();
#pragma unroll
  for (int j = 0; j < 32; j += 8)
    out[(long)(c0 + ty + j) * ldout + r0 + tx] = tile[tx][ty + j];
}

// straight cast f32 -> bf16
__global__ void k_cast(const float* __restrict__ in, bf16* __restrict__ out, long n) {
  long i = (long)blockIdx.x * 256 + threadIdx.x;
  if (i < n) out[i] = __float2bfloat16(in[i]);
}

// kpad[h][512+t][d] = qkv[t][512 + h*64 + d]
__global__ void k_packk(const bf16* __restrict__ qkv, bf16* __restrict__ kpad) {
  int idx = blockIdx.x * 256 + threadIdx.x;  // 8*2048*64
  int d = idx & 63, t = (idx >> 6) & 2047, h = idx >> 17;
  kpad[(long)h * 163840 + (512 + t) * 64 + d] = qkv[(long)t * 1536 + 512 + h * 64 + d];
}

// zero kpad[h][0:512][:] and vtpad[:][0:512]
__global__ void k_zeropad(bf16* __restrict__ kpad, bf16* __restrict__ vtpad) {
  int idx = blockIdx.x * 256 + threadIdx.x;  // 524288
  bf16 z = __float2bfloat16(0.0f);
  if (idx < 262144) {
    int h = idx >> 15, off = idx & 32767;
    kpad[(long)h * 163840 + off] = z;
  } else {
    int i = idx - 262144;
    int f = i >> 9, j = i & 511;
    vtpad[(long)f * 2560 + j] = z;
  }
}

// in-place masked softmax over bf16 score rows: SP = softmax(SP*0.125, window mask)
__global__ void k_softmax(bf16* __restrict__ SP) {
  int row = blockIdx.x;  // (h*4+w)*512 + i
  int i = row & 511;
  int limit = i + 513;  // mask: j <= i + 512
  bf16* s = SP + (long)row * 1024;
  int tid = threadIdx.x;
  float v[4];
  float mx = -1e30f;
#pragma unroll
  for (int c = 0; c < 4; ++c) {
    int j = c * 256 + tid;
    float xv = (j < limit) ? __bfloat162float(s[j]) * 0.125f : -1e30f;
    v[c] = xv;
    mx = fmaxf(mx, xv);
  }
  mx = block_max(mx);
  float sum = 0.f;
#pragma unroll
  for (int c = 0; c < 4; ++c) {
    float e = (v[c] <= -1e29f) ? 0.f : expf(v[c] - mx);
    v[c] = e;
    sum += e;
  }
  sum = block_sum(sum);
  float inv = 1.0f / sum;
#pragma unroll
  for (int c = 0; c < 4; ++c) {
    int j = c * 256 + tid;
    s[j] = __float2bfloat16(v[c] * inv);  // each thread rewrites only its own elems
  }
}

// final LN + head, all f32
__global__ void k_head(const float* __restrict__ x, const float* __restrict__ sc,
                       const float* __restrict__ w, const float* __restrict__ b,
                       float* __restrict__ out) {
  int row = blockIdx.x, tid = threadIdx.x;
  __shared__ float xn[1024];
  const float* p = x + (long)row * 1024;
  float loc[4];
  float s = 0.f;
#pragma unroll
  for (int c = 0; c < 4; ++c) {
    float v = p[c * 256 + tid];
    loc[c] = v;
    s += v;
  }
  s = block_sum(s);
  float mean = s / 1024.f;
  float s2 = 0.f;
#pragma unroll
  for (int c = 0; c < 4; ++c) {
    float d = loc[c] - mean;
    s2 += d * d;
  }
  s2 = block_sum(s2);
  float inv = 1.0f / sqrtf(s2 / 1024.f + 1e-5f);
#pragma unroll
  for (int c = 0; c < 4; ++c) {
    int j = c * 256 + tid;
    xn[j] = (loc[c] - mean) * inv * sc[j];
  }
  __syncthreads();
  int t = tid & 31, sl = tid >> 5;
  float partial = 0.f;
  for (int kk = 0; kk < 128; ++kk) {
    int k = sl * 128 + kk;
    partial += xn[k] * w[k * 32 + t];
  }
  __shared__ float red[256];
  red[tid] = partial;
  __syncthreads();
  if (tid < 32) {
    float r = 0.f;
    for (int q = 0; q < 8; ++q) r += red[q * 32 + t];
    out[(long)row * 32 + t] = r + b[t];
  }
}

// ---------------------------------------------------------------------------
extern "C" void kernel_launch(void* const* d_in, const int* in_sizes, int n_in,
                              void* d_out, int out_size, void* d_ws, size_t ws_size,
                              hipStream_t stream) {
  (void)in_sizes; (void)n_in; (void)out_size; (void)ws_size;
  const int*   tokens   = (const int*)d_in[0];
  const float* embed    = (const float*)d_in[1];
  const float* attn_ln  = (const float*)d_in[2];
  const float* attn_qkv = (const float*)d_in[3];
  const float* attn_ow  = (const float*)d_in[4];
  const float* attn_ob  = (const float*)d_in[5];
  const float* ff_ln    = (const float*)d_in[6];
  const float* ff_w1    = (const float*)d_in[7];
  const float* ff_b1    = (const float*)d_in[8];
  const float* ff_w2    = (const float*)d_in[9];
  const float* ff_b2    = (const float*)d_in[10];
  const float* g_ln     = (const float*)d_in[11];
  const float* g_win    = (const float*)d_in[12];
  const float* g_bin    = (const float*)d_in[13];
  const float* g_sln    = (const float*)d_in[14];
  const float* g_sw     = (const float*)d_in[15];
  const float* g_sb     = (const float*)d_in[16];
  const float* g_sow    = (const float*)d_in[17];
  const float* g_sob    = (const float*)d_in[18];
  const float* g_pow    = (const float*)d_in[19];
  const float* g_pob    = (const float*)d_in[20];
  const float* fin_ln   = (const float*)d_in[21];
  const float* head_w   = (const float*)d_in[22];
  const float* head_b   = (const float*)d_in[23];

  // ---- workspace layout (peak 79,691,776 bytes) ----
  char* ws = (char*)d_ws;
  float* x  = (float*)ws;                          // 8,388,608 B f32 [2048][1024]
  bf16* xn  = (bf16*)(ws + 8388608);               // 4,194,304 B
  char* SC  = ws + 12582912;                       // 50,331,648 B phase scratch
  // attention-phase
  bf16* qkv   = (bf16*)SC;                         // 6,291,456 B [2048][1536]
  bf16* kpad  = (bf16*)(SC + 6291456);             // 2,621,440 B [8][2560][64]
  bf16* vtpad = (bf16*)(SC + 8912896);             // 2,621,440 B [8][64][2560]
  bf16* SP    = (bf16*)(SC + 11534336);            // 33,554,432 B [32][512][1024] in-place scores->probs
  bf16* att   = (bf16*)(SC + 45088768);            // 2,097,152 B [2048][512]
  // ff / gmlp-phase (aliases attention scratch)
  bf16* h      = (bf16*)SC;                        // 16,777,216 B [2048][4096]
  bf16* gateLN = (bf16*)(SC + 16777216);           // 8,388,608 B
  bf16* gateT  = (bf16*)(SC + 25165824);           // 8,388,608 B
  bf16* prod   = (bf16*)(SC + 33554432);           // 8,388,608 B
  bf16* sbuf   = (bf16*)(SC + 41943040);           // 8,388,608 B
  // rotating transposed-weight buffers (strictly sequential use)
  bf16* W  = (bf16*)(ws + 62914560);               // 8,388,608 B
  bf16* W2 = (bf16*)(ws + 71303168);               // 8,388,608 B -> ends 79,691,776

  k_embed<<<2048, 256, 0, stream>>>(tokens, embed, x);

  for (int L = 0; L < 6; ++L) {
    const float* qkvw = attn_qkv + (long)L * 1024 * 1536;
    const float* oww  = attn_ow + (long)L * 512 * 1024;
    const float* w1   = ff_w1 + (long)L * 1024 * 4096;
    const float* w2   = ff_w2 + (long)L * 4096 * 1024;

    k_ln<float><<<2048, 256, 0, stream>>>(x, 1024, attn_ln + L * 1024, xn, 1024, 1024);
    k_transpose<float><<<dim3(48, 32), 256, 0, stream>>>(qkvw, 1536, W, 1024, 1024, 1536);
    gemm_bt<128, 128, 0><<<dim3(12, 16, 1), 256, 0, stream>>>(
        xn, 1024, 0, 0, W, 1024, 0, 0, qkv, 1536, 0, 0,
        2048, 1536, 1024, 1, nullptr, nullptr, nullptr, 0, nullptr, 0, 0, 0);

    k_packk<<<4096, 256, 0, stream>>>(qkv, kpad);
    k_zeropad<<<2048, 256, 0, stream>>>(kpad, vtpad);
    k_transpose<bf16><<<dim3(16, 64), 256, 0, stream>>>(qkv + 1024, 1536, vtpad + 512, 2560, 2048, 512);

    // SP[hw][i][j] = q . k  (scale+mask applied in softmax)
    gemm_bt<128, 128, 0><<<dim3(8, 4, 32), 256, 0, stream>>>(
        qkv, 1536, 64, 786432, kpad, 64, 163840, 32768, SP, 1024, 2097152, 524288,
        512, 1024, 64, 4, nullptr, nullptr, nullptr, 0, nullptr, 0, 0, 0);
    k_softmax<<<16384, 256, 0, stream>>>(SP);
    // att[w*512+i][h*64+d] = P . V
    gemm_bt<128, 64, 0><<<dim3(1, 4, 32), 128, 0, stream>>>(
        SP, 1024, 2097152, 524288, vtpad, 2560, 163840, 512, att, 512, 64, 262144,
        512, 64, 1024, 4, nullptr, nullptr, nullptr, 0, nullptr, 0, 0, 0);
    // x += att @ ow + ob   (split-K: 2 chunks of 256 -> 256 blocks)
    k_transpose<float><<<dim3(32, 16), 256, 0, stream>>>(oww, 1024, W, 512, 512, 1024);
    gemm_bt<128, 128, 3><<<dim3(16, 16, 1), 256, 0, stream>>>(
        att, 512, 0, 0, W, 512, 0, 0, nullptr, 1024, 0, 0,
        2048, 1024, 512, 1, attn_ob + L * 1024, nullptr, nullptr, 0, x, 0, 8, 256);

    // FF
    k_ln<float><<<2048, 256, 0, stream>>>(x, 1024, ff_ln + L * 1024, xn, 1024, 1024);
    k_transpose<float><<<dim3(128, 32), 256, 0, stream>>>(w1, 4096, W, 1024, 1024, 4096);
    gemm_bt<128, 128, 2><<<dim3(32, 16, 1), 256, 0, stream>>>(
        xn, 1024, 0, 0, W, 1024, 0, 0, h, 4096, 0, 0,
        2048, 4096, 1024, 1, ff_b1 + L * 4096, nullptr, nullptr, 0, nullptr, 0, 0, 0);
    k_transpose<float><<<dim3(32, 128), 256, 0, stream>>>(w2, 1024, W, 4096, 4096, 1024);
    // x += h @ w2 + b2   (split-K: 4 chunks of 1024 -> 512 blocks)
    gemm_bt<128, 128, 3><<<dim3(32, 16, 1), 256, 0, stream>>>(
        h, 4096, 0, 0, W, 4096, 0, 0, nullptr, 1024, 0, 0,
        2048, 1024, 4096, 1, ff_b2 + L * 1024, nullptr, nullptr, 0, x, 0, 8, 1024);
  }

  for (int G = 0; G < 2; ++G) {
    const float* winw = g_win + (long)G * 1024 * 4096;
    const float* soww = g_sow + (long)G * 2048 * 2048;
    const float* poww = g_pow + (long)G * 2048 * 1024;

    k_ln<float><<<2048, 256, 0, stream>>>(x, 1024, g_ln + G * 1024, xn, 1024, 1024);
    k_transpose<float><<<dim3(128, 32), 256, 0, stream>>>(winw, 4096, W, 1024, 1024, 4096);
    gemm_bt<128, 128, 2><<<dim3(32, 16, 1), 256, 0, stream>>>(
        xn, 1024, 0, 0, W, 1024, 0, 0, h, 4096, 0, 0,
        2048, 4096, 1024, 1, g_bin + G * 4096, nullptr, nullptr, 0, nullptr, 0, 0, 0);
    // gate = ln(h[:,2048:]) ; transpose for spatial GEMM
    k_ln<bf16><<<2048, 256, 0, stream>>>(h + 2048, 4096, g_sln + G * 2048, gateLN, 2048, 2048);
    k_transpose<bf16><<<dim3(64, 64), 256, 0, stream>>>(gateLN, 2048, gateT, 2048, 2048, 2048);
    // spatial gate weights: cast f32 sw -> bf16 (W2)
    k_cast<<<16384, 256, 0, stream>>>(g_sw + (long)G * 2048 * 2048, W2, 4194304L);
    // prod[m][d] = (sum_{n<=m} sw[m][n]*gate[n][d] + sb[m]) * xg[m][d]
    gemm_bt<128, 128, 4><<<dim3(16, 16, 1), 256, 0, stream>>>(
        W2, 2048, 0, 0, gateT, 2048, 0, 0, prod, 2048, 0, 0,
        2048, 2048, 2048, 1, nullptr, g_sb + G * 2048, h, 4096, nullptr, 1, 0, 0);
    k_transpose<float><<<dim3(64, 64), 256, 0, stream>>>(soww, 2048, W, 2048, 2048, 2048);
    gemm_bt<128, 128, 0><<<dim3(16, 16, 1), 256, 0, stream>>>(
        prod, 2048, 0, 0, W, 2048, 0, 0, sbuf, 2048, 0, 0,
        2048, 2048, 2048, 1, g_sob + G * 2048, nullptr, nullptr, 0, nullptr, 0, 0, 0);
    k_transpose<float><<<dim3(32, 64), 256, 0, stream>>>(poww, 1024, W, 2048, 2048, 1024);
    // x += sbuf @ pow + pob   (split-K: 4 chunks of 512 -> 512 blocks)
    gemm_bt<128, 128, 3><<<dim3(32, 16, 1), 256, 0, stream>>>(
        sbuf, 2048, 0, 0, W, 2048, 0, 0, nullptr, 1024, 0, 0,
        2048, 1024, 2048, 1, g_pob + G * 1024, nullptr, nullptr, 0, x, 0, 8, 512);
  }

  k_head<<<2048, 256, 0, stream>>>(x, fin_ln, head_w, head_b, (float*)d_out);
}